// Round 5
// baseline (254.531 us; speedup 1.0000x reference)
//
#include <hip/hip_runtime.h>
#include <math.h>

typedef __attribute__((ext_vector_type(8)))  _Float16 half8;
typedef __attribute__((ext_vector_type(4)))  float    f32x4;
typedef __attribute__((ext_vector_type(16))) float    f32x16;

constexpr int D_DIM = 2048;
constexpr int NEXP  = 64;
constexpr int TOPK  = 8;
constexpr int NTOK  = 16384;        // B*S
constexpr int TM    = 64;           // tokens per WG
constexpr int BK    = 64;           // K per staged chunk (4 MFMA ksteps of K=16)
constexpr int NCH   = D_DIM / BK;   // 32 chunks
constexpr int OSTR  = 132;          // logit tile row stride (floats)
constexpr float WSCALE  = 4096.0f;
constexpr float INV_WSC = 1.0f / 4096.0f;

__device__ __forceinline__ unsigned short f16b(float x) {
    _Float16 h = (_Float16)x;                       // v_cvt_f16_f32 (RNE)
    return __builtin_bit_cast(unsigned short, h);
}
__device__ __forceinline__ float f16tof(unsigned short b) {
    return (float)__builtin_bit_cast(_Float16, b);
}
__device__ __forceinline__ f32x4 ntload4(const float* p) {
    return __builtin_nontemporal_load(reinterpret_cast<const f32x4*>(p));
}

// ---------------------------------------------------------------------------
// K1: W*4096 (gate rows 0..63, noise rows 64..127) split fp16 hi/lo, packed
// for 32x32x16 B-fragments:
//   [kstep16 kk (stride 4096)][ntile32 nt (stride 1024)]{ hi 512 | lo 512 }
//   lane l holds B[k = kk*16 + (l>>5)*8 + j][n = nt*32 + (l&31)]
// ---------------------------------------------------------------------------
__global__ void prep_w(const float* __restrict__ Wg, const float* __restrict__ Wn,
                       unsigned short* __restrict__ wsB)
{
    const int idx = blockIdx.x * blockDim.x + threadIdx.x;   // 0..32767
    const int n   = idx >> 8;      // output row 0..127
    const int K8  = idx & 255;     // k-octet
    const float* src = (n < 64) ? (Wg + (size_t)n * D_DIM)
                                : (Wn + (size_t)(n - 64) * D_DIM);
    f32x4 a = *reinterpret_cast<const f32x4*>(src + K8 * 8);
    f32x4 b = *reinterpret_cast<const f32x4*>(src + K8 * 8 + 4);

    float v[8] = {a[0], a[1], a[2], a[3], b[0], b[1], b[2], b[3]};
    union { unsigned short u[8]; half8 s; } H, L;
#pragma unroll
    for (int j = 0; j < 8; ++j) {
        float xs = v[j] * WSCALE;
        unsigned short h = f16b(xs);
        H.u[j] = h;
        L.u[j] = f16b(xs - f16tof(h));
    }
    const int kk   = K8 >> 1;             // kstep16 index 0..127
    const int koct = K8 & 1;              // k-octet within kstep
    const int lane = koct * 32 + (n & 31);
    const size_t base = (size_t)kk * 4096 + (size_t)(n >> 5) * 1024 + (size_t)lane * 8;
    *reinterpret_cast<half8*>(wsB + base)       = H.s;
    *reinterpret_cast<half8*>(wsB + base + 512) = L.s;
}

// ---------------------------------------------------------------------------
// K2 v5b: pipe-work reduction. mfma 32x32x16 (halves A LDS reads per FLOP),
// TM=64, 8 waves = (mt 0..1) x (nt 0..3), grid 256 (1 WG/CU).
// A staged in LDS fragment-linear with XOR unit-swizzle (conflict-free reads
// AND writes). B reg-double-buffered one chunk ahead (L2 latency hidden).
// hs/nz loads nontemporal so the 1MB wsB stays L2-resident.
// LDS: 2 stage bufs x 8192 ushorts (32 KB) union'd with 64x132 f32 logits.
// ---------------------------------------------------------------------------
__global__ __launch_bounds__(512, 2)
void noisy_topk_router(const float* __restrict__ hs,
                       const unsigned short* __restrict__ wsB,
                       const float* __restrict__ nz,
                       float* __restrict__ out)
{
    __shared__ __align__(16) char smem[33792];
    unsigned short* stage  = reinterpret_cast<unsigned short*>(smem);
    float*          logits = reinterpret_cast<float*>(smem);

    const int tid  = threadIdx.x;
    const int lane = tid & 63;
    const int w    = tid >> 6;
    const int mt   = w & 1;             // m-tile: tokens mt*32..+31
    const int nt   = w >> 1;            // n-tile: experts nt*32..+31
    const int t0   = blockIdx.x * TM;

    // --- A-fragment read addressing: lane l reads logical 16B unit u=l of
    //     frag(ks,mt,h); physical unit = l ^ ks ^ ((l>>5)<<2).
    const int lxr = lane ^ ((lane >> 5) << 2);

    // --- staging role: thread t -> row r = t>>3 (0..63), k-octet q = t&7 ---
    const int r    = tid >> 3;
    const int q    = tid & 7;
    const int ks_w = q >> 1;
    const int koct = q & 1;
    const int uphys = ((koct << 5) + (r & 31)) ^ ks_w ^ (koct << 2);
    const int woff  = (ks_w * 2 + (r >> 5)) * 1024 + uphys * 8;   // ushort units
    const float* hrow = hs + (size_t)(t0 + r) * D_DIM + q * 8;

    // --- B base: wsB + kk*4096 + nt*1024 + lane*8 ---
    const unsigned short* bbase = wsB + (size_t)nt * 1024 + (size_t)lane * 8;

    f32x16 accP, accX0, accX1;
#pragma unroll
    for (int i = 0; i < 16; ++i) { accP[i] = 0.f; accX0[i] = 0.f; accX1[i] = 0.f; }

    half8 bh0[4], bl0[4], bh1[4], bl1[4];

    auto loadB = [&](int chunk, half8* bh, half8* bl) {
#pragma unroll
        for (int ks = 0; ks < 4; ++ks) {
            const unsigned short* p = bbase + (size_t)(chunk * 4 + ks) * 4096;
            bh[ks] = *reinterpret_cast<const half8*>(p);
            bl[ks] = *reinterpret_cast<const half8*>(p + 512);
        }
    };

    auto cvt_write = [&](f32x4 a, f32x4 b, unsigned short* buf) {
        float v[8] = {a[0], a[1], a[2], a[3], b[0], b[1], b[2], b[3]};
        union { unsigned short u[8]; half8 s; } H, L;
#pragma unroll
        for (int j = 0; j < 8; ++j) {
            unsigned short h = f16b(v[j]);
            H.u[j] = h;
            L.u[j] = f16b(v[j] - f16tof(h));
        }
        *reinterpret_cast<half8*>(buf + woff)       = H.s;
        *reinterpret_cast<half8*>(buf + woff + 512) = L.s;
    };

    auto body = [&](const half8* bh, const half8* bl, const unsigned short* sb) {
#pragma unroll
        for (int ks = 0; ks < 4; ++ks) {
            const int off = (ks * 2 + mt) * 1024 + (lxr ^ ks) * 8;
            half8 ahi = *reinterpret_cast<const half8*>(sb + off);
            half8 alo = *reinterpret_cast<const half8*>(sb + off + 512);
            accP  = __builtin_amdgcn_mfma_f32_32x32x16_f16(ahi, bh[ks], accP,  0, 0, 0);
            accX0 = __builtin_amdgcn_mfma_f32_32x32x16_f16(ahi, bl[ks], accX0, 0, 0, 0);
            accX1 = __builtin_amdgcn_mfma_f32_32x32x16_f16(alo, bh[ks], accX1, 0, 0, 0);
        }
    };

    // prologue: B chunk 0 + stage chunk 0
    loadB(0, bh0, bl0);
    cvt_write(ntload4(hrow), ntload4(hrow + 4), stage);
    __syncthreads();

#pragma unroll 1
    for (int cc = 0; cc < NCH / 2; ++cc) {
        const int e = 2 * cc;
        // ---- chunk e (uses bh0/bl0, stage buf0) ----
        loadB(e + 1, bh1, bl1);
        __builtin_amdgcn_sched_barrier(0);
        f32x4 pa = ntload4(hrow + (e + 1) * BK);
        f32x4 pb = ntload4(hrow + (e + 1) * BK + 4);
        __builtin_amdgcn_sched_barrier(0);
        body(bh0, bl0, stage);
        cvt_write(pa, pb, stage + 8192);
        __syncthreads();

        // ---- chunk e+1 (uses bh1/bl1, stage buf1) ----
        const bool more = (e + 2) < NCH;
        f32x4 pa2, pb2;
        if (more) {
            loadB(e + 2, bh0, bl0);
            __builtin_amdgcn_sched_barrier(0);
            pa2 = ntload4(hrow + (e + 2) * BK);
            pb2 = ntload4(hrow + (e + 2) * BK + 4);
            __builtin_amdgcn_sched_barrier(0);
        }
        body(bh1, bl1, stage + 8192);
        if (more)
            cvt_write(pa2, pb2, stage);
        __syncthreads();
    }

    // ---- epilogue: accs -> logit tile (stage region is dead now) ----
    {
        const int colb  = nt * 32 + (lane & 31);
        const int rbase = mt * 32 + 4 * (lane >> 5);
#pragma unroll
        for (int rr = 0; rr < 16; ++rr) {
            const int row = rbase + (rr & 3) + 8 * (rr >> 2);
            logits[row * OSTR + colb] = (accP[rr] + accX0[rr] + accX1[rr]) * INV_WSC;
        }
    }
    __syncthreads();

    // ---- wave-parallel epilogue: wave w owns tokens w*8..w*8+7,
    //      expert-per-lane (lane = expert e) ----
    float* gout = out + (size_t)NTOK * TOPK * 2;
    for (int tt = 0; tt < 8; ++tt) {
        const int tl  = w * 8 + tt;
        const int tok = t0 + tl;
        float gsc = logits[tl * OSTR + lane];
        float nl  = logits[tl * OSTR + 64 + lane];
        float nzv = __builtin_nontemporal_load(nz + (size_t)tok * NEXP + lane);
        float sp  = fmaxf(nl, 0.0f) + log1pf(expf(-fabsf(nl)));   // softplus
        float le  = fmaf(nzv, sp, gsc);

        float mx = le;
#pragma unroll
        for (int d = 32; d > 0; d >>= 1) mx = fmaxf(mx, __shfl_xor(mx, d));
        float pe = expf(le - mx);
        float s  = pe;
#pragma unroll
        for (int d = 32; d > 0; d >>= 1) s += __shfl_xor(s, d);
        float g = pe * (1.0f / s);

        gout[(size_t)tok * NEXP + lane] = g;

        // top-8 by repeated wave argmax; tie-break: lowest index
        float v = g;
        float keepv = 0.0f;
        int   keepi = 0;
#pragma unroll
        for (int it = 0; it < TOPK; ++it) {
            float m  = v;
            int   mi = lane;
#pragma unroll
            for (int d = 32; d > 0; d >>= 1) {
                float om = __shfl_xor(m, d);
                int   oi = __shfl_xor(mi, d);
                bool take = (om > m) || (om == m && oi < mi);
                m  = take ? om : m;
                mi = take ? oi : mi;
            }
            if (lane == it) { keepv = m; keepi = mi; }
            if (lane == mi) v = -1.0f;      // extracted; gates>0 so never re-wins
        }
        if (lane < TOPK) {
            out[(size_t)tok * TOPK + lane] = keepv;
            out[(size_t)NTOK * TOPK + (size_t)tok * TOPK + lane] = (float)keepi;
        }
    }
}

extern "C" void kernel_launch(void* const* d_in, const int* in_sizes, int n_in,
                              void* d_out, int out_size, void* d_ws, size_t ws_size,
                              hipStream_t stream) {
    const float* hs = (const float*)d_in[0];   // [4,4096,2048]
    const float* Wg = (const float*)d_in[1];   // [64,2048]
    const float* Wn = (const float*)d_in[2];   // [64,2048]
    const float* nz = (const float*)d_in[3];   // [4,4096,64]
    float* out = (float*)d_out;
    unsigned short* wsB = (unsigned short*)d_ws;   // 1 MB B-fragment pack

    prep_w<<<64, 512, 0, stream>>>(Wg, Wn, wsB);
    noisy_topk_router<<<NTOK / TM, 512, 0, stream>>>(hs, wsB, nz, out);
}